// Round 9
// baseline (638.929 us; speedup 1.0000x reference)
//
#include <hip/hip_runtime.h>
#include <hip/hip_bf16.h>
#include <math.h>

#define D 2048
#define NH 16
#define NKV 4
#define HD 128
#define NE 16
#define NI 768
#define S 1024
#define EPS 1e-6f

typedef __attribute__((ext_vector_type(8))) short bf16x8;
typedef __attribute__((ext_vector_type(4))) float f32x4;

__device__ __forceinline__ float wave_reduce_sum64(float v) {
    for (int off = 32; off; off >>= 1) v += __shfl_xor(v, off, 64);
    return v;
}

__device__ __forceinline__ unsigned short f2bf(float f) {
    unsigned int x = __float_as_uint(f);
    x += 0x7FFFu + ((x >> 16) & 1u);   // round-to-nearest-even
    return (unsigned short)(x >> 16);
}

__device__ __forceinline__ bf16x8 pack8(const float4 a, const float4 b) {
    bf16x8 r;
    r[0] = (short)f2bf(a.x); r[1] = (short)f2bf(a.y);
    r[2] = (short)f2bf(a.z); r[3] = (short)f2bf(a.w);
    r[4] = (short)f2bf(b.x); r[5] = (short)f2bf(b.y);
    r[6] = (short)f2bf(b.z); r[7] = (short)f2bf(b.w);
    return r;
}

// ---------------------------------------------------------------- RMSNorm over D (+ optional bf16 copy)
__global__ void rmsnorm_kernel(const float* __restrict__ x, const float* __restrict__ w,
                               float* __restrict__ y, unsigned short* __restrict__ yb) {
    int t = blockIdx.x;
    const float* xr = x + (size_t)t * D;
    float* yr = y + (size_t)t * D;
    float v[8];
    float ss = 0.f;
#pragma unroll
    for (int m = 0; m < 8; ++m) {
        v[m] = xr[threadIdx.x + 256 * m];
        ss += v[m] * v[m];
    }
    ss = wave_reduce_sum64(ss);
    __shared__ float wsum[4];
    if ((threadIdx.x & 63) == 0) wsum[threadIdx.x >> 6] = ss;
    __syncthreads();
    float tot = wsum[0] + wsum[1] + wsum[2] + wsum[3];
    float r = rsqrtf(tot / (float)D + EPS);
#pragma unroll
    for (int m = 0; m < 8; ++m) {
        int d = threadIdx.x + 256 * m;
        float val = v[m] * r * w[d];
        yr[d] = val;
        if (yb) yb[(size_t)t * D + d] = f2bf(val);
    }
}

// ---------------------------------------------------------------- dense MFMA GEMM (LDS dbuf, 1 barrier/k-step)
__global__ __launch_bounds__(256) void mfma_gemm_kernel(
    const float* __restrict__ A, int lda,
    const float* __restrict__ W, int ldw,
    float* __restrict__ C, int ldc,
    const float* __restrict__ R, float* __restrict__ C2,
    int M, int N, int K)
{
    int m0 = blockIdx.y * 64;
    int n0 = blockIdx.x * 64;

    __shared__ unsigned short As[2][64 * 64];
    __shared__ unsigned short Bs[2][64 * 64];

    int tid = threadIdx.x;
    int srow = tid >> 2;
    int scol = (tid & 3) * 16;

    const float* ap = A + (size_t)(m0 + srow) * lda + scol;
    const float* wp = W + (size_t)(n0 + srow) * ldw + scol;

    int wlo[2];
#pragma unroll
    for (int u = 0; u < 2; ++u) {
        int g = (tid & 3) * 2 + u;
        wlo[u] = srow * 64 + (g ^ (srow & 7)) * 8;
    }

    int wid = tid >> 6, lane = tid & 63;
    int wm = wid >> 1, wn = wid & 1;
    int l16 = lane & 15, lhi = lane >> 4;

    int ra[2][2], rb[2][2];
#pragma unroll
    for (int f = 0; f < 2; ++f) {
        int rowa = wm * 32 + f * 16 + l16;
        int rowb = wn * 32 + f * 16 + l16;
#pragma unroll
        for (int kh = 0; kh < 2; ++kh) {
            ra[f][kh] = rowa * 64 + (((kh * 4 + lhi) ^ (rowa & 7))) * 8;
            rb[f][kh] = rowb * 64 + (((kh * 4 + lhi) ^ (rowb & 7))) * 8;
        }
    }

    f32x4 acc[2][2] = {};
    float4 avA[4], wvA[4], avB[4], wvB[4];

    auto ldt = [&](float4* av, float4* wv, int k0) {
#pragma unroll
        for (int u = 0; u < 4; ++u) {
            av[u] = *(const float4*)(ap + k0 + u * 4);
            wv[u] = *(const float4*)(wp + k0 + u * 4);
        }
    };
    auto stage = [&](const float4* av, const float4* wv, int b) {
        bf16x8 pa0 = pack8(av[0], av[1]);
        bf16x8 pa1 = pack8(av[2], av[3]);
        bf16x8 pw0 = pack8(wv[0], wv[1]);
        bf16x8 pw1 = pack8(wv[2], wv[3]);
        *(bf16x8*)(&As[b][wlo[0]]) = pa0;
        *(bf16x8*)(&As[b][wlo[1]]) = pa1;
        *(bf16x8*)(&Bs[b][wlo[0]]) = pw0;
        *(bf16x8*)(&Bs[b][wlo[1]]) = pw1;
    };
    auto domfma = [&](int b) {
#pragma unroll
        for (int kh = 0; kh < 2; ++kh) {
            bf16x8 af0 = *(const bf16x8*)(&As[b][ra[0][kh]]);
            bf16x8 af1 = *(const bf16x8*)(&As[b][ra[1][kh]]);
            bf16x8 bf0 = *(const bf16x8*)(&Bs[b][rb[0][kh]]);
            bf16x8 bf1 = *(const bf16x8*)(&Bs[b][rb[1][kh]]);
            acc[0][0] = __builtin_amdgcn_mfma_f32_16x16x32_bf16(af0, bf0, acc[0][0], 0, 0, 0);
            acc[0][1] = __builtin_amdgcn_mfma_f32_16x16x32_bf16(af0, bf1, acc[0][1], 0, 0, 0);
            acc[1][0] = __builtin_amdgcn_mfma_f32_16x16x32_bf16(af1, bf0, acc[1][0], 0, 0, 0);
            acc[1][1] = __builtin_amdgcn_mfma_f32_16x16x32_bf16(af1, bf1, acc[1][1], 0, 0, 0);
        }
    };

    ldt(avA, wvA, 0);
    for (int k0 = 0; k0 < K; k0 += 128) {
        ldt(avB, wvB, k0 + 64);
        stage(avA, wvA, 0);
        __syncthreads();
        domfma(0);
        if (k0 + 128 < K) ldt(avA, wvA, k0 + 128);
        stage(avB, wvB, 1);
        __syncthreads();
        domfma(1);
    }

#pragma unroll
    for (int mi = 0; mi < 2; ++mi) {
#pragma unroll
        for (int r = 0; r < 4; ++r) {
            int grow = m0 + wm * 32 + mi * 16 + lhi * 4 + r;
#pragma unroll
            for (int ni = 0; ni < 2; ++ni) {
                int gcol = n0 + wn * 32 + ni * 16 + l16;
                float v = acc[mi][ni][r];
                if (R) v += R[(size_t)grow * ldc + gcol];
                C[(size_t)grow * ldc + gcol] = v;
                if (C2) C2[(size_t)grow * ldc + gcol] = v;
            }
        }
    }
}

// ---------------------------------------------------------------- fused QKV GEMM (LDS dbuf)
__global__ __launch_bounds__(256) void qkv_gemm_kernel(
    const float* __restrict__ A,
    const float* __restrict__ Wq, const float* __restrict__ Wk, const float* __restrict__ Wv,
    float* __restrict__ C)
{
    int m0 = blockIdx.y * 64;
    int n0 = blockIdx.x * 64;

    const float* W;
    int wr0;
    if (n0 < 2048)      { W = Wq; wr0 = n0; }
    else if (n0 < 2560) { W = Wk; wr0 = n0 - 2048; }
    else                { W = Wv; wr0 = n0 - 2560; }

    __shared__ unsigned short As[2][64 * 64];
    __shared__ unsigned short Bs[2][64 * 64];

    int tid = threadIdx.x;
    int srow = tid >> 2;
    int scol = (tid & 3) * 16;

    const float* ap = A + (size_t)(m0 + srow) * D + scol;
    const float* wp = W + (size_t)(wr0 + srow) * D + scol;

    int wlo[2];
#pragma unroll
    for (int u = 0; u < 2; ++u) {
        int g = (tid & 3) * 2 + u;
        wlo[u] = srow * 64 + (g ^ (srow & 7)) * 8;
    }

    int wid = tid >> 6, lane = tid & 63;
    int wm = wid >> 1, wn = wid & 1;
    int l16 = lane & 15, lhi = lane >> 4;

    int ra[2][2], rb[2][2];
#pragma unroll
    for (int f = 0; f < 2; ++f) {
        int rowa = wm * 32 + f * 16 + l16;
        int rowb = wn * 32 + f * 16 + l16;
#pragma unroll
        for (int kh = 0; kh < 2; ++kh) {
            ra[f][kh] = rowa * 64 + (((kh * 4 + lhi) ^ (rowa & 7))) * 8;
            rb[f][kh] = rowb * 64 + (((kh * 4 + lhi) ^ (rowb & 7))) * 8;
        }
    }

    f32x4 acc[2][2] = {};
    float4 avA[4], wvA[4], avB[4], wvB[4];

    auto ldt = [&](float4* av, float4* wv, int k0) {
#pragma unroll
        for (int u = 0; u < 4; ++u) {
            av[u] = *(const float4*)(ap + k0 + u * 4);
            wv[u] = *(const float4*)(wp + k0 + u * 4);
        }
    };
    auto stage = [&](const float4* av, const float4* wv, int b) {
        bf16x8 pa0 = pack8(av[0], av[1]);
        bf16x8 pa1 = pack8(av[2], av[3]);
        bf16x8 pw0 = pack8(wv[0], wv[1]);
        bf16x8 pw1 = pack8(wv[2], wv[3]);
        *(bf16x8*)(&As[b][wlo[0]]) = pa0;
        *(bf16x8*)(&As[b][wlo[1]]) = pa1;
        *(bf16x8*)(&Bs[b][wlo[0]]) = pw0;
        *(bf16x8*)(&Bs[b][wlo[1]]) = pw1;
    };
    auto domfma = [&](int b) {
#pragma unroll
        for (int kh = 0; kh < 2; ++kh) {
            bf16x8 af0 = *(const bf16x8*)(&As[b][ra[0][kh]]);
            bf16x8 af1 = *(const bf16x8*)(&As[b][ra[1][kh]]);
            bf16x8 bf0 = *(const bf16x8*)(&Bs[b][rb[0][kh]]);
            bf16x8 bf1 = *(const bf16x8*)(&Bs[b][rb[1][kh]]);
            acc[0][0] = __builtin_amdgcn_mfma_f32_16x16x32_bf16(af0, bf0, acc[0][0], 0, 0, 0);
            acc[0][1] = __builtin_amdgcn_mfma_f32_16x16x32_bf16(af0, bf1, acc[0][1], 0, 0, 0);
            acc[1][0] = __builtin_amdgcn_mfma_f32_16x16x32_bf16(af1, bf0, acc[1][0], 0, 0, 0);
            acc[1][1] = __builtin_amdgcn_mfma_f32_16x16x32_bf16(af1, bf1, acc[1][1], 0, 0, 0);
        }
    };

    ldt(avA, wvA, 0);
    for (int k0 = 0; k0 < D; k0 += 128) {
        ldt(avB, wvB, k0 + 64);
        stage(avA, wvA, 0);
        __syncthreads();
        domfma(0);
        if (k0 + 128 < D) ldt(avA, wvA, k0 + 128);
        stage(avB, wvB, 1);
        __syncthreads();
        domfma(1);
    }

#pragma unroll
    for (int mi = 0; mi < 2; ++mi) {
#pragma unroll
        for (int r = 0; r < 4; ++r) {
            int grow = m0 + wm * 32 + mi * 16 + lhi * 4 + r;
#pragma unroll
            for (int ni = 0; ni < 2; ++ni) {
                int gcol = n0 + wn * 32 + ni * 16 + l16;
                C[(size_t)grow * 3072 + gcol] = acc[mi][ni][r];
            }
        }
    }
}

// ---------------------------------------------------------------- fused MoE up+gate (gathered, barrier-free)
// BM=64, BN=16. A and B fragments loaded DIRECT from global per-lane;
// no LDS tiles, no k-loop barriers, register double-buffer.
__global__ __launch_bounds__(256) void moe_mlp_kernel(
    const unsigned short* __restrict__ h2b,
    const float* __restrict__ Wg, const float* __restrict__ Wu,
    const int* __restrict__ cnt, const int* __restrict__ elist,
    unsigned short* __restrict__ abuf)
{
    int e = blockIdx.z;
    int me = cnt[e];
    int m0 = blockIdx.y * 64;
    if (m0 >= me) return;
    int n0 = blockIdx.x * 16;

    __shared__ int ridx[64];
    int tid = threadIdx.x;
    const int* idx = elist + e * S;
    if (tid < 64) ridx[tid] = (m0 + tid < me) ? idx[m0 + tid] : -1;
    __syncthreads();

    int wid = tid >> 6, lane = tid & 63;
    int l16 = lane & 15, lhi = lane >> 4;

    // A: lane's fixed token row; granule lhi (kh=0) and 4+lhi (kh=1)
    int arv = ridx[wid * 16 + l16];
    const unsigned short* aptr = h2b + (size_t)((arv < 0 ? 0 : arv) >> 1) * D + lhi * 8;
    // B: lane's fixed weight rows (n0+l16), granule kh*4+lhi
    const float* gptr = Wg + ((size_t)e * NI + n0 + l16) * D + lhi * 8;
    const float* uptr = Wu + ((size_t)e * NI + n0 + l16) * D + lhi * 8;

    f32x4 accg = {}, accu = {};
    bf16x8 aA[2], aB[2];
    float4 gA[4], uA[4], gB[4], uB[4];

    auto ldt = [&](bf16x8* a, float4* g, float4* u, int k0) {
        a[0] = *(const bf16x8*)(aptr + k0);
        a[1] = *(const bf16x8*)(aptr + k0 + 32);
#pragma unroll
        for (int kh = 0; kh < 2; ++kh) {
            g[kh * 2 + 0] = *(const float4*)(gptr + k0 + kh * 32);
            g[kh * 2 + 1] = *(const float4*)(gptr + k0 + kh * 32 + 4);
            u[kh * 2 + 0] = *(const float4*)(uptr + k0 + kh * 32);
            u[kh * 2 + 1] = *(const float4*)(uptr + k0 + kh * 32 + 4);
        }
    };
    auto domfma = [&](const bf16x8* a, const float4* g, const float4* u) {
#pragma unroll
        for (int kh = 0; kh < 2; ++kh) {
            bf16x8 bg = pack8(g[kh * 2], g[kh * 2 + 1]);
            bf16x8 bu = pack8(u[kh * 2], u[kh * 2 + 1]);
            accg = __builtin_amdgcn_mfma_f32_16x16x32_bf16(a[kh], bg, accg, 0, 0, 0);
            accu = __builtin_amdgcn_mfma_f32_16x16x32_bf16(a[kh], bu, accu, 0, 0, 0);
        }
    };

    ldt(aA, gA, uA, 0);
    for (int k0 = 0; k0 < D; k0 += 128) {
        ldt(aB, gB, uB, k0 + 64);
        domfma(aA, gA, uA);
        if (k0 + 128 < D) ldt(aA, gA, uA, k0 + 128);
        domfma(aB, gB, uB);
    }

#pragma unroll
    for (int r = 0; r < 4; ++r) {
        int lrow = wid * 16 + lhi * 4 + r;
        int rv = ridx[lrow];
        if (rv < 0) continue;
        float g = accg[r];
        float u = accu[r];
        float a = g / (1.f + __expf(-g)) * u;
        abuf[(size_t)rv * NI + n0 + l16] = f2bf(a);
    }
}

// ---------------------------------------------------------------- MoE down proj + combine (barrier-free)
// BM=64, BN=16. A direct from abuf; B direct from Wd. out += w * acc via atomics.
__global__ __launch_bounds__(256) void moe_down_kernel(
    const unsigned short* __restrict__ abuf, const float* __restrict__ Wd,
    const int* __restrict__ cnt, const int* __restrict__ elist,
    const float* __restrict__ wbuf, float* __restrict__ out)
{
    int e = blockIdx.z;
    int me = cnt[e];
    int m0 = blockIdx.y * 64;
    if (m0 >= me) return;
    int n0 = blockIdx.x * 16;

    __shared__ int ridx[64];
    int tid = threadIdx.x;
    const int* idx = elist + e * S;
    if (tid < 64) ridx[tid] = (m0 + tid < me) ? idx[m0 + tid] : -1;
    __syncthreads();

    int wid = tid >> 6, lane = tid & 63;
    int l16 = lane & 15, lhi = lane >> 4;

    int arv = ridx[wid * 16 + l16];
    const unsigned short* aptr = abuf + (size_t)(arv < 0 ? 0 : arv) * NI + lhi * 8;
    const float* bptr = Wd + ((size_t)e * D + n0 + l16) * NI + lhi * 8;

    f32x4 acc = {};
    bf16x8 aA[2], aB[2];
    float4 bA[4], bB[4];

    auto ldt = [&](bf16x8* a, float4* b, int k0) {
        a[0] = *(const bf16x8*)(aptr + k0);
        a[1] = *(const bf16x8*)(aptr + k0 + 32);
#pragma unroll
        for (int kh = 0; kh < 2; ++kh) {
            b[kh * 2 + 0] = *(const float4*)(bptr + k0 + kh * 32);
            b[kh * 2 + 1] = *(const float4*)(bptr + k0 + kh * 32 + 4);
        }
    };
    auto domfma = [&](const bf16x8* a, const float4* b) {
#pragma unroll
        for (int kh = 0; kh < 2; ++kh) {
            bf16x8 bb = pack8(b[kh * 2], b[kh * 2 + 1]);
            acc = __builtin_amdgcn_mfma_f32_16x16x32_bf16(a[kh], bb, acc, 0, 0, 0);
        }
    };

    ldt(aA, bA, 0);
    for (int k0 = 0; k0 < NI; k0 += 128) {
        ldt(aB, bB, k0 + 64);
        domfma(aA, bA);
        if (k0 + 128 < NI) ldt(aA, bA, k0 + 128);
        domfma(aB, bB);
    }

#pragma unroll
    for (int r = 0; r < 4; ++r) {
        int lrow = wid * 16 + lhi * 4 + r;
        int rv = ridx[lrow];
        if (rv < 0) continue;
        float w = wbuf[rv];
        atomicAdd(out + (size_t)(rv >> 1) * D + n0 + l16, w * acc[r]);
    }
}

// ---------------------------------------------------------------- q/k RMSNorm + RoPE -> bf16
__global__ void qkrope_bf16_kernel(const float* __restrict__ qkvb,
                                   const float* __restrict__ qn_w, const float* __restrict__ kn_w,
                                   const int* __restrict__ pos_ids,
                                   unsigned short* __restrict__ qbh, unsigned short* __restrict__ kbh)
{
    int t = blockIdx.x;
    int h = blockIdx.y;
    int d = threadIdx.x;
    const float* base;
    const float* w;
    unsigned short* ob;
    float scale;
    if (h < NH) {
        base = qkvb + (size_t)t * 3072 + h * HD; w = qn_w;
        ob = qbh + (size_t)t * D + h * HD; scale = 0.08838834764831845f;
    } else {
        base = qkvb + (size_t)t * 3072 + 2048 + (h - NH) * HD; w = kn_w;
        ob = kbh + (size_t)t * (NKV * HD) + (h - NH) * HD; scale = 1.0f;
    }
    float x1 = base[d], x2 = base[d + 64];
    float ss = wave_reduce_sum64(x1 * x1 + x2 * x2);
    float r = rsqrtf(ss / (float)HD + EPS);
    float n1 = x1 * r * w[d];
    float n2 = x2 * r * w[d + 64];
    float pos = (float)pos_ids[t];
    float freq = powf(1000000.0f, -(float)d * (1.0f / 64.0f));
    float ang = pos * freq;
    float c, s;
    sincosf(ang, &s, &c);
    ob[d]      = f2bf((n1 * c - n2 * s) * scale);
    ob[d + 64] = f2bf((n2 * c + n1 * s) * scale);
}

// ---------------------------------------------------------------- V -> bf16 V^T [KV][HD][S]
__global__ void vtrans_kernel(const float* __restrict__ qkvb, unsigned short* __restrict__ vbt)
{
    __shared__ unsigned short tile[64][65];
    int s0 = blockIdx.x * 64, d0 = blockIdx.y * 64, kvh = blockIdx.z;
    int tid = threadIdx.x;
    {
        int i = tid >> 2;
        int j4 = (tid & 3) * 16;
        const float* src = qkvb + (size_t)(s0 + i) * 3072 + 2560 + kvh * HD + d0 + j4;
#pragma unroll
        for (int u = 0; u < 4; ++u) {
            float4 f = *(const float4*)(src + u * 4);
            tile[i][j4 + u * 4 + 0] = f2bf(f.x);
            tile[i][j4 + u * 4 + 1] = f2bf(f.y);
            tile[i][j4 + u * 4 + 2] = f2bf(f.z);
            tile[i][j4 + u * 4 + 3] = f2bf(f.w);
        }
    }
    __syncthreads();
    {
        int j = tid >> 2;
        int i4 = (tid & 3) * 16;
        bf16x8 o0, o1;
#pragma unroll
        for (int u = 0; u < 8; ++u) {
            o0[u] = (short)tile[i4 + u][j];
            o1[u] = (short)tile[i4 + 8 + u][j];
        }
        unsigned short* dst = vbt + ((size_t)kvh * HD + d0 + j) * S + s0 + i4;
        *(bf16x8*)(dst) = o0;
        *(bf16x8*)(dst + 8) = o1;
    }
}

// ---------------------------------------------------------------- MFMA flash attention
__global__ __launch_bounds__(256) void flash_attn_mfma_kernel(
    const unsigned short* __restrict__ qbh, const unsigned short* __restrict__ kbh,
    const unsigned short* __restrict__ vbt, float* __restrict__ o)
{
    int qt = blockIdx.x;
    int h  = blockIdx.y;
    int kvh = h >> 2;

    __shared__ unsigned short Qs[64 * 128];
    __shared__ unsigned short Ks[64 * 128];
    __shared__ unsigned short Vs[128 * 64];
    __shared__ unsigned short Ps[4][16 * 72];

    int tid = threadIdx.x;
    int wid = tid >> 6, lane = tid & 63;
    int l16 = lane & 15, lhi = lane >> 4;

    {
        int r = tid >> 2;
        int gb = (tid & 3) * 4;
        const unsigned short* src = qbh + (size_t)(qt * 64 + r) * D + h * HD;
#pragma unroll
        for (int u = 0; u < 4; ++u) {
            int g = gb + u;
            bf16x8 val = *(const bf16x8*)(src + g * 8);
            *(bf16x8*)(Qs + r * 128 + (g ^ (r & 7)) * 8) = val;
        }
    }

    int qrow = wid * 16 + l16;
    int qoff[4];
#pragma unroll
    for (int kh = 0; kh < 4; ++kh)
        qoff[kh] = qrow * 128 + (((kh * 4 + lhi) ^ (qrow & 7))) * 8;

    float mreg[4], lreg[4];
#pragma unroll
    for (int r = 0; r < 4; ++r) { mreg[r] = -3.0e38f; lreg[r] = 0.f; }
    f32x4 oacc[8] = {};

    for (int kt = 0; kt < S / 64; ++kt) {
        __syncthreads();
        {
            int r = tid >> 2;
            int gb = (tid & 3) * 4;
            const unsigned short* src = kbh + (size_t)(kt * 64 + r) * (NKV * HD) + kvh * HD;
#pragma unroll
            for (int u = 0; u < 4; ++u) {
                int g = gb + u;
                bf16x8 val = *(const bf16x8*)(src + g * 8);
                *(bf16x8*)(Ks + r * 128 + (g ^ (r & 7)) * 8) = val;
            }
        }
        {
            int r = tid >> 1;
            int gb = (tid & 1) * 4;
            const unsigned short* src = vbt + ((size_t)kvh * HD + r) * S + kt * 64;
#pragma unroll
            for (int u = 0; u < 4; ++u) {
                int g = gb + u;
                bf16x8 val = *(const bf16x8*)(src + g * 8);
                *(bf16x8*)(Vs + r * 64 + (g ^ (r & 7)) * 8) = val;
            }
        }
        __syncthreads();

        bf16x8 qa[4];
#pragma unroll
        for (int kh = 0; kh < 4; ++kh) qa[kh] = *(const bf16x8*)(Qs + qoff[kh]);
        f32x4 sc[4] = {};
#pragma unroll
        for (int nf = 0; nf < 4; ++nf) {
            int krow = nf * 16 + l16;
#pragma unroll
            for (int kh = 0; kh < 4; ++kh) {
                bf16x8 kf = *(const bf16x8*)(Ks + krow * 128 + (((kh * 4 + lhi) ^ (krow & 7))) * 8);
                sc[nf] = __builtin_amdgcn_mfma_f32_16x16x32_bf16(qa[kh], kf, sc[nf], 0, 0, 0);
            }
        }

        float corr[4];
#pragma unroll
        for (int r = 0; r < 4; ++r) {
            float tmax = fmaxf(fmaxf(sc[0][r], sc[1][r]), fmaxf(sc[2][r], sc[3][r]));
            tmax = fmaxf(tmax, __shfl_xor(tmax, 1, 64));
            tmax = fmaxf(tmax, __shfl_xor(tmax, 2, 64));
            tmax = fmaxf(tmax, __shfl_xor(tmax, 4, 64));
            tmax = fmaxf(tmax, __shfl_xor(tmax, 8, 64));
            float mn = fmaxf(mreg[r], tmax);
            corr[r] = __expf(mreg[r] - mn);
            mreg[r] = mn;
            float psum = 0.f;
#pragma unroll
            for (int nf = 0; nf < 4; ++nf) {
                float p = __expf(sc[nf][r] - mn);
                sc[nf][r] = p;
                psum += p;
            }
            psum += __shfl_xor(psum, 1, 64);
            psum += __shfl_xor(psum, 2, 64);
            psum += __shfl_xor(psum, 4, 64);
            psum += __shfl_xor(psum, 8, 64);
            lreg[r] = lreg[r] * corr[r] + psum;
        }
#pragma unroll
        for (int fb = 0; fb < 8; ++fb)
#pragma unroll
            for (int r = 0; r < 4; ++r) oacc[fb][r] *= corr[r];

#pragma unroll
        for (int nf = 0; nf < 4; ++nf)
#pragma unroll
            for (int r = 0; r < 4; ++r)
                Ps[wid][(lhi * 4 + r) * 72 + nf * 16 + l16] = f2bf(sc[nf][r]);

        bf16x8 pa[2];
#pragma unroll
        for (int k2 = 0; k2 < 2; ++k2)
            pa[k2] = *(const bf16x8*)(&Ps[wid][l16 * 72 + k2 * 32 + lhi * 8]);

#pragma unroll
        for (int fb = 0; fb < 8; ++fb) {
            int vrow = fb * 16 + l16;
#pragma unroll
            for (int k2 = 0; k2 < 2; ++k2) {
                bf16x8 vf = *(const bf16x8*)(Vs + vrow * 64 + (((k2 * 4 + lhi) ^ (vrow & 7))) * 8);
                oacc[fb] = __builtin_amdgcn_mfma_f32_16x16x32_bf16(pa[k2], vf, oacc[fb], 0, 0, 0);
            }
        }
    }

    float linv[4];
#pragma unroll
    for (int r = 0; r < 4; ++r) linv[r] = 1.f / lreg[r];
#pragma unroll
    for (int fb = 0; fb < 8; ++fb) {
#pragma unroll
        for (int r = 0; r < 4; ++r) {
            int row = qt * 64 + wid * 16 + lhi * 4 + r;
            o[(size_t)row * D + h * HD + fb * 16 + l16] = oacc[fb][r] * linv[r];
        }
    }
}

// ---------------------------------------------------------------- MoE gate + expert lists
__global__ void gate_kernel(const float* __restrict__ x, const float* __restrict__ gw,
                            float* __restrict__ wbuf, int* __restrict__ cnt, int* __restrict__ elist)
{
    int t = blockIdx.x;
    int g = threadIdx.x >> 4, j = threadIdx.x & 15;
    const float* xr = x + (size_t)t * D;
    const float* gr = gw + (size_t)g * D;
    float p = 0.f;
    for (int m = 0; m < D / 16; ++m) p += xr[j + 16 * m] * gr[j + 16 * m];
    for (int off = 8; off; off >>= 1) p += __shfl_down(p, off, 64);
    __shared__ float lg[NE];
    if (j == 0) lg[g] = p;
    __syncthreads();
    if (threadIdx.x == 0) {
        float l0 = -1e30f; int i0 = 0;
        for (int e = 0; e < NE; ++e) if (lg[e] > l0) { l0 = lg[e]; i0 = e; }
        float l1 = -1e30f; int i1 = 0;
        for (int e = 0; e < NE; ++e) if (e != i0 && lg[e] > l1) { l1 = lg[e]; i1 = e; }
        float rr = expf(l1 - l0);
        wbuf[t * 2 + 0] = 1.f / (1.f + rr);
        wbuf[t * 2 + 1] = rr / (1.f + rr);
        int s0 = atomicAdd(&cnt[i0], 1); elist[i0 * S + s0] = t * 2;
        int s1 = atomicAdd(&cnt[i1], 1); elist[i1 * S + s1] = t * 2 + 1;
    }
}

// ---------------------------------------------------------------- launch
extern "C" void kernel_launch(void* const* d_in, const int* in_sizes, int n_in,
                              void* d_out, int out_size, void* d_ws, size_t ws_size,
                              hipStream_t stream)
{
    const float* hidden = (const float*)d_in[0];
    const float* ln1 = (const float*)d_in[1];
    const float* ln2 = (const float*)d_in[2];
    const float* qn  = (const float*)d_in[3];
    const float* kn  = (const float*)d_in[4];
    const float* Wq  = (const float*)d_in[5];
    const float* Wk  = (const float*)d_in[6];
    const float* Wv  = (const float*)d_in[7];
    const float* Wo  = (const float*)d_in[8];
    const float* gw  = (const float*)d_in[9];
    const float* Wg  = (const float*)d_in[10];
    const float* Wu  = (const float*)d_in[11];
    const float* Wd  = (const float*)d_in[12];
    const int*   pos = (const int*)d_in[13];

    float* ws    = (float*)d_ws;
    float* h1    = ws;                    // 2M floats; overlays qbh/kbh/vbt bf16
    float* qkvb  = h1 + 2097152;          // S*3072 = 3.15M floats
    float* attn  = qkvb + 3145728;        // 2M; overlays abuf bf16
    float* hattn = attn + 2097152;        // 2M
    float* h2    = hattn + 2097152;       // 2M
    float* h2bf  = h2 + 2097152;          // 1M floats as bf16 (S*D ushort)
    float* wbuf  = h2bf + 1048576;        // 2048
    int*   cnt   = (int*)(wbuf + 2048);   // 16
    int*   elist = cnt + 16;              // 16*1024

    unsigned short* qbh = (unsigned short*)h1;                 // S*D bf16
    unsigned short* kbh = (unsigned short*)(h1 + 1048576);     // S*512 bf16
    unsigned short* vbt = (unsigned short*)(h1 + 1310720);     // 512*S bf16
    unsigned short* abuf = (unsigned short*)attn;              // 2048*NI bf16
    unsigned short* h2b  = (unsigned short*)h2bf;              // S*D bf16
    float* out   = (float*)d_out;

    hipMemsetAsync(cnt, 0, NE * sizeof(int), stream);

    rmsnorm_kernel<<<S, 256, 0, stream>>>(hidden, ln1, h1, nullptr);
    qkv_gemm_kernel<<<dim3(48, 16), 256, 0, stream>>>(h1, Wq, Wk, Wv, qkvb);
    // h1 dead; bf16 overlays
    qkrope_bf16_kernel<<<dim3(S, NH + NKV), 64, 0, stream>>>(qkvb, qn, kn, pos, qbh, kbh);
    vtrans_kernel<<<dim3(S / 64, HD / 64, NKV), 256, 0, stream>>>(qkvb, vbt);
    flash_attn_mfma_kernel<<<dim3(S / 64, NH), 256, 0, stream>>>(qbh, kbh, vbt, attn);
    // O projection + residual; also writes out (= hattn) for MoE atomic accumulation
    mfma_gemm_kernel<<<dim3(32, 16), 256, 0, stream>>>(attn, D, Wo, D, hattn, D, hidden, out, S, 2048, D);
    rmsnorm_kernel<<<S, 256, 0, stream>>>(hattn, ln2, h2, h2b);
    gate_kernel<<<S, 256, 0, stream>>>(h2, gw, wbuf, cnt, elist);
    // attn buffer dead; abuf overlays
    moe_mlp_kernel<<<dim3(NI / 16, 16, NE), 256, 0, stream>>>(h2b, Wg, Wu, cnt, elist, abuf);
    moe_down_kernel<<<dim3(D / 16, 16, NE), 256, 0, stream>>>(abuf, Wd, cnt, elist, wbuf, out);
}

// Round 10
// 344.289 us; speedup vs baseline: 1.8558x; 1.8558x over previous
//
#include <hip/hip_runtime.h>
#include <hip/hip_bf16.h>
#include <math.h>

#define D 2048
#define NH 16
#define NKV 4
#define HD 128
#define NE 16
#define NI 768
#define S 1024
#define EPS 1e-6f

typedef __attribute__((ext_vector_type(8))) short bf16x8;
typedef __attribute__((ext_vector_type(4))) float f32x4;

__device__ __forceinline__ float wave_reduce_sum64(float v) {
    for (int off = 32; off; off >>= 1) v += __shfl_xor(v, off, 64);
    return v;
}

__device__ __forceinline__ unsigned short f2bf(float f) {
    unsigned int x = __float_as_uint(f);
    x += 0x7FFFu + ((x >> 16) & 1u);   // round-to-nearest-even
    return (unsigned short)(x >> 16);
}

__device__ __forceinline__ bf16x8 pack8(const float4 a, const float4 b) {
    bf16x8 r;
    r[0] = (short)f2bf(a.x); r[1] = (short)f2bf(a.y);
    r[2] = (short)f2bf(a.z); r[3] = (short)f2bf(a.w);
    r[4] = (short)f2bf(b.x); r[5] = (short)f2bf(b.y);
    r[6] = (short)f2bf(b.z); r[7] = (short)f2bf(b.w);
    return r;
}

// async 16B-per-lane global -> LDS (wave-uniform LDS base + lane*16)
__device__ __forceinline__ void async16(const void* src, void* dst_lds) {
    __builtin_amdgcn_global_load_lds(
        (const __attribute__((address_space(1))) unsigned int*)src,
        (__attribute__((address_space(3))) unsigned int*)dst_lds,
        16, 0, 0);
}

// ---------------------------------------------------------------- RMSNorm over D (+ optional bf16 copy)
__global__ void rmsnorm_kernel(const float* __restrict__ x, const float* __restrict__ w,
                               float* __restrict__ y, unsigned short* __restrict__ yb) {
    int t = blockIdx.x;
    const float* xr = x + (size_t)t * D;
    float* yr = y + (size_t)t * D;
    float v[8];
    float ss = 0.f;
#pragma unroll
    for (int m = 0; m < 8; ++m) {
        v[m] = xr[threadIdx.x + 256 * m];
        ss += v[m] * v[m];
    }
    ss = wave_reduce_sum64(ss);
    __shared__ float wsum[4];
    if ((threadIdx.x & 63) == 0) wsum[threadIdx.x >> 6] = ss;
    __syncthreads();
    float tot = wsum[0] + wsum[1] + wsum[2] + wsum[3];
    float r = rsqrtf(tot / (float)D + EPS);
#pragma unroll
    for (int m = 0; m < 8; ++m) {
        int d = threadIdx.x + 256 * m;
        float val = v[m] * r * w[d];
        yr[d] = val;
        if (yb) yb[(size_t)t * D + d] = f2bf(val);
    }
}

// ---------------------------------------------------------------- dense MFMA GEMM (LDS dbuf, 1 barrier/k-step)
__global__ __launch_bounds__(256) void mfma_gemm_kernel(
    const float* __restrict__ A, int lda,
    const float* __restrict__ W, int ldw,
    float* __restrict__ C, int ldc,
    const float* __restrict__ R, float* __restrict__ C2,
    int M, int N, int K)
{
    int m0 = blockIdx.y * 64;
    int n0 = blockIdx.x * 64;

    __shared__ unsigned short As[2][64 * 64];
    __shared__ unsigned short Bs[2][64 * 64];

    int tid = threadIdx.x;
    int srow = tid >> 2;
    int scol = (tid & 3) * 16;

    const float* ap = A + (size_t)(m0 + srow) * lda + scol;
    const float* wp = W + (size_t)(n0 + srow) * ldw + scol;

    int wlo[2];
#pragma unroll
    for (int u = 0; u < 2; ++u) {
        int g = (tid & 3) * 2 + u;
        wlo[u] = srow * 64 + (g ^ (srow & 7)) * 8;
    }

    int wid = tid >> 6, lane = tid & 63;
    int wm = wid >> 1, wn = wid & 1;
    int l16 = lane & 15, lhi = lane >> 4;

    int ra[2][2], rb[2][2];
#pragma unroll
    for (int f = 0; f < 2; ++f) {
        int rowa = wm * 32 + f * 16 + l16;
        int rowb = wn * 32 + f * 16 + l16;
#pragma unroll
        for (int kh = 0; kh < 2; ++kh) {
            ra[f][kh] = rowa * 64 + (((kh * 4 + lhi) ^ (rowa & 7))) * 8;
            rb[f][kh] = rowb * 64 + (((kh * 4 + lhi) ^ (rowb & 7))) * 8;
        }
    }

    f32x4 acc[2][2] = {};
    float4 avA[4], wvA[4], avB[4], wvB[4];

    auto ldt = [&](float4* av, float4* wv, int k0) {
#pragma unroll
        for (int u = 0; u < 4; ++u) {
            av[u] = *(const float4*)(ap + k0 + u * 4);
            wv[u] = *(const float4*)(wp + k0 + u * 4);
        }
    };
    auto stage = [&](const float4* av, const float4* wv, int b) {
        bf16x8 pa0 = pack8(av[0], av[1]);
        bf16x8 pa1 = pack8(av[2], av[3]);
        bf16x8 pw0 = pack8(wv[0], wv[1]);
        bf16x8 pw1 = pack8(wv[2], wv[3]);
        *(bf16x8*)(&As[b][wlo[0]]) = pa0;
        *(bf16x8*)(&As[b][wlo[1]]) = pa1;
        *(bf16x8*)(&Bs[b][wlo[0]]) = pw0;
        *(bf16x8*)(&Bs[b][wlo[1]]) = pw1;
    };
    auto domfma = [&](int b) {
#pragma unroll
        for (int kh = 0; kh < 2; ++kh) {
            bf16x8 af0 = *(const bf16x8*)(&As[b][ra[0][kh]]);
            bf16x8 af1 = *(const bf16x8*)(&As[b][ra[1][kh]]);
            bf16x8 bf0 = *(const bf16x8*)(&Bs[b][rb[0][kh]]);
            bf16x8 bf1 = *(const bf16x8*)(&Bs[b][rb[1][kh]]);
            acc[0][0] = __builtin_amdgcn_mfma_f32_16x16x32_bf16(af0, bf0, acc[0][0], 0, 0, 0);
            acc[0][1] = __builtin_amdgcn_mfma_f32_16x16x32_bf16(af0, bf1, acc[0][1], 0, 0, 0);
            acc[1][0] = __builtin_amdgcn_mfma_f32_16x16x32_bf16(af1, bf0, acc[1][0], 0, 0, 0);
            acc[1][1] = __builtin_amdgcn_mfma_f32_16x16x32_bf16(af1, bf1, acc[1][1], 0, 0, 0);
        }
    };

    ldt(avA, wvA, 0);
    for (int k0 = 0; k0 < K; k0 += 128) {
        ldt(avB, wvB, k0 + 64);
        stage(avA, wvA, 0);
        __syncthreads();
        domfma(0);
        if (k0 + 128 < K) ldt(avA, wvA, k0 + 128);
        stage(avB, wvB, 1);
        __syncthreads();
        domfma(1);
    }

#pragma unroll
    for (int mi = 0; mi < 2; ++mi) {
#pragma unroll
        for (int r = 0; r < 4; ++r) {
            int grow = m0 + wm * 32 + mi * 16 + lhi * 4 + r;
#pragma unroll
            for (int ni = 0; ni < 2; ++ni) {
                int gcol = n0 + wn * 32 + ni * 16 + l16;
                float v = acc[mi][ni][r];
                if (R) v += R[(size_t)grow * ldc + gcol];
                C[(size_t)grow * ldc + gcol] = v;
                if (C2) C2[(size_t)grow * ldc + gcol] = v;
            }
        }
    }
}

// ---------------------------------------------------------------- fused QKV GEMM (LDS dbuf)
__global__ __launch_bounds__(256) void qkv_gemm_kernel(
    const float* __restrict__ A,
    const float* __restrict__ Wq, const float* __restrict__ Wk, const float* __restrict__ Wv,
    float* __restrict__ C)
{
    int m0 = blockIdx.y * 64;
    int n0 = blockIdx.x * 64;

    const float* W;
    int wr0;
    if (n0 < 2048)      { W = Wq; wr0 = n0; }
    else if (n0 < 2560) { W = Wk; wr0 = n0 - 2048; }
    else                { W = Wv; wr0 = n0 - 2560; }

    __shared__ unsigned short As[2][64 * 64];
    __shared__ unsigned short Bs[2][64 * 64];

    int tid = threadIdx.x;
    int srow = tid >> 2;
    int scol = (tid & 3) * 16;

    const float* ap = A + (size_t)(m0 + srow) * D + scol;
    const float* wp = W + (size_t)(wr0 + srow) * D + scol;

    int wlo[2];
#pragma unroll
    for (int u = 0; u < 2; ++u) {
        int g = (tid & 3) * 2 + u;
        wlo[u] = srow * 64 + (g ^ (srow & 7)) * 8;
    }

    int wid = tid >> 6, lane = tid & 63;
    int wm = wid >> 1, wn = wid & 1;
    int l16 = lane & 15, lhi = lane >> 4;

    int ra[2][2], rb[2][2];
#pragma unroll
    for (int f = 0; f < 2; ++f) {
        int rowa = wm * 32 + f * 16 + l16;
        int rowb = wn * 32 + f * 16 + l16;
#pragma unroll
        for (int kh = 0; kh < 2; ++kh) {
            ra[f][kh] = rowa * 64 + (((kh * 4 + lhi) ^ (rowa & 7))) * 8;
            rb[f][kh] = rowb * 64 + (((kh * 4 + lhi) ^ (rowb & 7))) * 8;
        }
    }

    f32x4 acc[2][2] = {};
    float4 avA[4], wvA[4], avB[4], wvB[4];

    auto ldt = [&](float4* av, float4* wv, int k0) {
#pragma unroll
        for (int u = 0; u < 4; ++u) {
            av[u] = *(const float4*)(ap + k0 + u * 4);
            wv[u] = *(const float4*)(wp + k0 + u * 4);
        }
    };
    auto stage = [&](const float4* av, const float4* wv, int b) {
        bf16x8 pa0 = pack8(av[0], av[1]);
        bf16x8 pa1 = pack8(av[2], av[3]);
        bf16x8 pw0 = pack8(wv[0], wv[1]);
        bf16x8 pw1 = pack8(wv[2], wv[3]);
        *(bf16x8*)(&As[b][wlo[0]]) = pa0;
        *(bf16x8*)(&As[b][wlo[1]]) = pa1;
        *(bf16x8*)(&Bs[b][wlo[0]]) = pw0;
        *(bf16x8*)(&Bs[b][wlo[1]]) = pw1;
    };
    auto domfma = [&](int b) {
#pragma unroll
        for (int kh = 0; kh < 2; ++kh) {
            bf16x8 af0 = *(const bf16x8*)(&As[b][ra[0][kh]]);
            bf16x8 af1 = *(const bf16x8*)(&As[b][ra[1][kh]]);
            bf16x8 bf0 = *(const bf16x8*)(&Bs[b][rb[0][kh]]);
            bf16x8 bf1 = *(const bf16x8*)(&Bs[b][rb[1][kh]]);
            acc[0][0] = __builtin_amdgcn_mfma_f32_16x16x32_bf16(af0, bf0, acc[0][0], 0, 0, 0);
            acc[0][1] = __builtin_amdgcn_mfma_f32_16x16x32_bf16(af0, bf1, acc[0][1], 0, 0, 0);
            acc[1][0] = __builtin_amdgcn_mfma_f32_16x16x32_bf16(af1, bf0, acc[1][0], 0, 0, 0);
            acc[1][1] = __builtin_amdgcn_mfma_f32_16x16x32_bf16(af1, bf1, acc[1][1], 0, 0, 0);
        }
    };

    ldt(avA, wvA, 0);
    for (int k0 = 0; k0 < D; k0 += 128) {
        ldt(avB, wvB, k0 + 64);
        stage(avA, wvA, 0);
        __syncthreads();
        domfma(0);
        if (k0 + 128 < D) ldt(avA, wvA, k0 + 128);
        stage(avB, wvB, 1);
        __syncthreads();
        domfma(1);
    }

#pragma unroll
    for (int mi = 0; mi < 2; ++mi) {
#pragma unroll
        for (int r = 0; r < 4; ++r) {
            int grow = m0 + wm * 32 + mi * 16 + lhi * 4 + r;
#pragma unroll
            for (int ni = 0; ni < 2; ++ni) {
                int gcol = n0 + wn * 32 + ni * 16 + l16;
                C[(size_t)grow * 3072 + gcol] = acc[mi][ni][r];
            }
        }
    }
}

// ---------------------------------------------------------------- fused MoE up+gate (async global_load_lds)
// BM=64, BN=16. A (bf16, gathered) + Wg/Wu (fp32) streamed direct-to-LDS, dbuf,
// 1 barrier/k-step. Pre-swizzled GLOBAL sources <-> swizzled LDS reads (rule #21).
__global__ __launch_bounds__(256) void moe_mlp_kernel(
    const unsigned short* __restrict__ h2b,
    const float* __restrict__ Wg, const float* __restrict__ Wu,
    const int* __restrict__ cnt, const int* __restrict__ elist,
    unsigned short* __restrict__ abuf)
{
    int e = blockIdx.z;
    int me = cnt[e];
    int m0 = blockIdx.y * 64;
    if (m0 >= me) return;
    int n0 = blockIdx.x * 16;

    __shared__ __align__(16) unsigned short As_[2][64 * 64];  // bf16 [row][64], swz g^(r&7) on 16B granules
    __shared__ __align__(16) float Gs_[2][16 * 64];           // fp32 [row][64], swz g^((r&7)*2)
    __shared__ __align__(16) float Us_[2][16 * 64];
    __shared__ int ridx[64];

    int tid = threadIdx.x;
    const int* idx = elist + e * S;
    if (tid < 64) ridx[tid] = (m0 + tid < me) ? idx[m0 + tid] : -1;
    __syncthreads();

    int wid = tid >> 6, lane = tid & 63;
    int l16 = lane & 15, lhi = lane >> 4;

    // ---- staging source addrs (pre-swizzled global): A two 16B instrs/wave-lane
    int ar0 = wid * 16 + (lane >> 3);
    int ar1 = ar0 + 8;
    int ag0 = (lane & 7) ^ (ar0 & 7);
    int ag1 = (lane & 7) ^ (ar1 & 7);
    int t0 = ridx[ar0], t1 = ridx[ar1];
    const unsigned short* asrc0 = h2b + (size_t)((t0 < 0 ? 0 : t0) >> 1) * D + ag0 * 8;
    const unsigned short* asrc1 = h2b + (size_t)((t1 < 0 ? 0 : t1) >> 1) * D + ag1 * 8;
    // B: one instr/wave per matrix; wave w covers rows w*4..w*4+3
    int brow = wid * 4 + (lane >> 4);
    int bg = (lane & 15) ^ ((brow & 7) * 2);
    const float* gsrc = Wg + ((size_t)e * NI + n0 + brow) * D + bg * 4;
    const float* usrc = Wu + ((size_t)e * NI + n0 + brow) * D + bg * 4;

    auto stage = [&](int b, int k0) {
        async16(asrc0 + k0, &As_[b][wid * 1024]);
        async16(asrc1 + k0, &As_[b][wid * 1024 + 512]);
        async16(gsrc + k0, &Gs_[b][wid * 256]);
        async16(usrc + k0, &Us_[b][wid * 256]);
    };

    // ---- fragment read offsets (swizzled)
    int rowa = wid * 16 + l16;
    int aoff[2], boff[2];
#pragma unroll
    for (int kh = 0; kh < 2; ++kh) {
        int j = kh * 4 + lhi;
        aoff[kh] = rowa * 64 + (j ^ (rowa & 7)) * 8;   // ushort units
        boff[kh] = l16 * 64 + (j ^ (l16 & 7)) * 8;     // float units
    }

    f32x4 accg = {}, accu = {};

    auto domfma = [&](int b) {
#pragma unroll
        for (int kh = 0; kh < 2; ++kh) {
            bf16x8 a = *(const bf16x8*)(&As_[b][aoff[kh]]);
            float4 g0 = *(const float4*)(&Gs_[b][boff[kh]]);
            float4 g1 = *(const float4*)(&Gs_[b][boff[kh] + 4]);
            float4 u0 = *(const float4*)(&Us_[b][boff[kh]]);
            float4 u1 = *(const float4*)(&Us_[b][boff[kh] + 4]);
            bf16x8 bg = pack8(g0, g1);
            bf16x8 bu = pack8(u0, u1);
            accg = __builtin_amdgcn_mfma_f32_16x16x32_bf16(a, bg, accg, 0, 0, 0);
            accu = __builtin_amdgcn_mfma_f32_16x16x32_bf16(a, bu, accu, 0, 0, 0);
        }
    };

    stage(0, 0);
    __syncthreads();
    for (int k0 = 0; k0 < D; k0 += 64) {
        int b = (k0 >> 6) & 1;
        if (k0 + 64 < D) stage(b ^ 1, k0 + 64);
        domfma(b);
        __syncthreads();
    }

#pragma unroll
    for (int r = 0; r < 4; ++r) {
        int lrow = wid * 16 + lhi * 4 + r;
        int rv = ridx[lrow];
        if (rv < 0) continue;
        float g = accg[r];
        float u = accu[r];
        float a = g / (1.f + __expf(-g)) * u;
        abuf[(size_t)rv * NI + n0 + l16] = f2bf(a);
    }
}

// ---------------------------------------------------------------- MoE down proj + combine (async global_load_lds)
__global__ __launch_bounds__(256) void moe_down_kernel(
    const unsigned short* __restrict__ abuf, const float* __restrict__ Wd,
    const int* __restrict__ cnt, const int* __restrict__ elist,
    const float* __restrict__ wbuf, float* __restrict__ out)
{
    int e = blockIdx.z;
    int me = cnt[e];
    int m0 = blockIdx.y * 64;
    if (m0 >= me) return;
    int n0 = blockIdx.x * 16;

    __shared__ __align__(16) unsigned short As_[2][64 * 64];
    __shared__ __align__(16) float Bs_[2][16 * 64];
    __shared__ int ridx[64];

    int tid = threadIdx.x;
    const int* idx = elist + e * S;
    if (tid < 64) ridx[tid] = (m0 + tid < me) ? idx[m0 + tid] : -1;
    __syncthreads();

    int wid = tid >> 6, lane = tid & 63;
    int l16 = lane & 15, lhi = lane >> 4;

    int ar0 = wid * 16 + (lane >> 3);
    int ar1 = ar0 + 8;
    int ag0 = (lane & 7) ^ (ar0 & 7);
    int ag1 = (lane & 7) ^ (ar1 & 7);
    int t0 = ridx[ar0], t1 = ridx[ar1];
    const unsigned short* asrc0 = abuf + (size_t)(t0 < 0 ? 0 : t0) * NI + ag0 * 8;
    const unsigned short* asrc1 = abuf + (size_t)(t1 < 0 ? 0 : t1) * NI + ag1 * 8;
    int brow = wid * 4 + (lane >> 4);
    int bg = (lane & 15) ^ ((brow & 7) * 2);
    const float* bsrc = Wd + ((size_t)e * D + n0 + brow) * NI + bg * 4;

    auto stage = [&](int b, int k0) {
        async16(asrc0 + k0, &As_[b][wid * 1024]);
        async16(asrc1 + k0, &As_[b][wid * 1024 + 512]);
        async16(bsrc + k0, &Bs_[b][wid * 256]);
    };

    int rowa = wid * 16 + l16;
    int aoff[2], boff[2];
#pragma unroll
    for (int kh = 0; kh < 2; ++kh) {
        int j = kh * 4 + lhi;
        aoff[kh] = rowa * 64 + (j ^ (rowa & 7)) * 8;
        boff[kh] = l16 * 64 + (j ^ (l16 & 7)) * 8;
    }

    f32x4 acc = {};

    auto domfma = [&](int b) {
#pragma unroll
        for (int kh = 0; kh < 2; ++kh) {
            bf16x8 a = *(const bf16x8*)(&As_[b][aoff[kh]]);
            float4 b0 = *(const float4*)(&Bs_[b][boff[kh]]);
            float4 b1 = *(const float4*)(&Bs_[b][boff[kh] + 4]);
            bf16x8 bb = pack8(b0, b1);
            acc = __builtin_amdgcn_mfma_f32_16x16x32_bf16(a, bb, acc, 0, 0, 0);
        }
    };

    stage(0, 0);
    __syncthreads();
    for (int k0 = 0; k0 < NI; k0 += 64) {
        int b = (k0 >> 6) & 1;
        if (k0 + 64 < NI) stage(b ^ 1, k0 + 64);
        domfma(b);
        __syncthreads();
    }

#pragma unroll
    for (int r = 0; r < 4; ++r) {
        int lrow = wid * 16 + lhi * 4 + r;
        int rv = ridx[lrow];
        if (rv < 0) continue;
        float w = wbuf[rv];
        atomicAdd(out + (size_t)(rv >> 1) * D + n0 + l16, w * acc[r]);
    }
}

// ---------------------------------------------------------------- q/k RMSNorm + RoPE -> bf16
__global__ void qkrope_bf16_kernel(const float* __restrict__ qkvb,
                                   const float* __restrict__ qn_w, const float* __restrict__ kn_w,
                                   const int* __restrict__ pos_ids,
                                   unsigned short* __restrict__ qbh, unsigned short* __restrict__ kbh)
{
    int t = blockIdx.x;
    int h = blockIdx.y;
    int d = threadIdx.x;
    const float* base;
    const float* w;
    unsigned short* ob;
    float scale;
    if (h < NH) {
        base = qkvb + (size_t)t * 3072 + h * HD; w = qn_w;
        ob = qbh + (size_t)t * D + h * HD; scale = 0.08838834764831845f;
    } else {
        base = qkvb + (size_t)t * 3072 + 2048 + (h - NH) * HD; w = kn_w;
        ob = kbh + (size_t)t * (NKV * HD) + (h - NH) * HD; scale = 1.0f;
    }
    float x1 = base[d], x2 = base[d + 64];
    float ss = wave_reduce_sum64(x1 * x1 + x2 * x2);
    float r = rsqrtf(ss / (float)HD + EPS);
    float n1 = x1 * r * w[d];
    float n2 = x2 * r * w[d + 64];
    float pos = (float)pos_ids[t];
    float freq = powf(1000000.0f, -(float)d * (1.0f / 64.0f));
    float ang = pos * freq;
    float c, s;
    sincosf(ang, &s, &c);
    ob[d]      = f2bf((n1 * c - n2 * s) * scale);
    ob[d + 64] = f2bf((n2 * c + n1 * s) * scale);
}

// ---------------------------------------------------------------- V -> bf16 V^T [KV][HD][S]
__global__ void vtrans_kernel(const float* __restrict__ qkvb, unsigned short* __restrict__ vbt)
{
    __shared__ unsigned short tile[64][65];
    int s0 = blockIdx.x * 64, d0 = blockIdx.y * 64, kvh = blockIdx.z;
    int tid = threadIdx.x;
    {
        int i = tid >> 2;
        int j4 = (tid & 3) * 16;
        const float* src = qkvb + (size_t)(s0 + i) * 3072 + 2560 + kvh * HD + d0 + j4;
#pragma unroll
        for (int u = 0; u < 4; ++u) {
            float4 f = *(const float4*)(src + u * 4);
            tile[i][j4 + u * 4 + 0] = f2bf(f.x);
            tile[i][j4 + u * 4 + 1] = f2bf(f.y);
            tile[i][j4 + u * 4 + 2] = f2bf(f.z);
            tile[i][j4 + u * 4 + 3] = f2bf(f.w);
        }
    }
    __syncthreads();
    {
        int j = tid >> 2;
        int i4 = (tid & 3) * 16;
        bf16x8 o0, o1;
#pragma unroll
        for (int u = 0; u < 8; ++u) {
            o0[u] = (short)tile[i4 + u][j];
            o1[u] = (short)tile[i4 + 8 + u][j];
        }
        unsigned short* dst = vbt + ((size_t)kvh * HD + d0 + j) * S + s0 + i4;
        *(bf16x8*)(dst) = o0;
        *(bf16x8*)(dst + 8) = o1;
    }
}

// ---------------------------------------------------------------- MFMA flash attention
__global__ __launch_bounds__(256) void flash_attn_mfma_kernel(
    const unsigned short* __restrict__ qbh, const unsigned short* __restrict__ kbh,
    const unsigned short* __restrict__ vbt, float* __restrict__ o)
{
    int qt = blockIdx.x;
    int h  = blockIdx.y;
    int kvh = h >> 2;

    __shared__ unsigned short Qs[64 * 128];
    __shared__ unsigned short Ks[64 * 128];
    __shared__ unsigned short Vs[128 * 64];
    __shared__ unsigned short Ps[4][16 * 72];

    int tid = threadIdx.x;
    int wid = tid >> 6, lane = tid & 63;
    int l16 = lane & 15, lhi = lane >> 4;

    {
        int r = tid >> 2;
        int gb = (tid & 3) * 4;
        const unsigned short* src = qbh + (size_t)(qt * 64 + r) * D + h * HD;
#pragma unroll
        for (int u = 0; u < 4; ++u) {
            int g = gb + u;
            bf16x8 val = *(const bf16x8*)(src + g * 8);
            *(bf16x8*)(Qs + r * 128 + (g ^ (r & 7)) * 8) = val;
        }
    }

    int qrow = wid * 16 + l16;
    int qoff[4];
#pragma unroll
    for (int kh = 0; kh < 4; ++kh)
        qoff[kh] = qrow * 128 + (((kh * 4 + lhi) ^ (qrow & 7))) * 8;

    float mreg[4], lreg[4];
#pragma unroll
    for (int r = 0; r < 4; ++r) { mreg[r] = -3.0e38f; lreg[r] = 0.f; }
    f32x4 oacc[8] = {};

    for (int kt = 0; kt < S / 64; ++kt) {
        __syncthreads();
        {
            int r = tid >> 2;
            int gb = (tid & 3) * 4;
            const unsigned short* src = kbh + (size_t)(kt * 64 + r) * (NKV * HD) + kvh * HD;
#pragma unroll
            for (int u = 0; u < 4; ++u) {
                int g = gb + u;
                bf16x8 val = *(const bf16x8*)(src + g * 8);
                *(bf16x8*)(Ks + r * 128 + (g ^ (r & 7)) * 8) = val;
            }
        }
        {
            int r = tid >> 1;
            int gb = (tid & 1) * 4;
            const unsigned short* src = vbt + ((size_t)kvh * HD + r) * S + kt * 64;
#pragma unroll
            for (int u = 0; u < 4; ++u) {
                int g = gb + u;
                bf16x8 val = *(const bf16x8*)(src + g * 8);
                *(bf16x8*)(Vs + r * 64 + (g ^ (r & 7)) * 8) = val;
            }
        }
        __syncthreads();

        bf16x8 qa[4];
#pragma unroll
        for (int kh = 0; kh < 4; ++kh) qa[kh] = *(const bf16x8*)(Qs + qoff[kh]);
        f32x4 sc[4] = {};
#pragma unroll
        for (int nf = 0; nf < 4; ++nf) {
            int krow = nf * 16 + l16;
#pragma unroll
            for (int kh = 0; kh < 4; ++kh) {
                bf16x8 kf = *(const bf16x8*)(Ks + krow * 128 + (((kh * 4 + lhi) ^ (krow & 7))) * 8);
                sc[nf] = __builtin_amdgcn_mfma_f32_16x16x32_bf16(qa[kh], kf, sc[nf], 0, 0, 0);
            }
        }

        float corr[4];
#pragma unroll
        for (int r = 0; r < 4; ++r) {
            float tmax = fmaxf(fmaxf(sc[0][r], sc[1][r]), fmaxf(sc[2][r], sc[3][r]));
            tmax = fmaxf(tmax, __shfl_xor(tmax, 1, 64));
            tmax = fmaxf(tmax, __shfl_xor(tmax, 2, 64));
            tmax = fmaxf(tmax, __shfl_xor(tmax, 4, 64));
            tmax = fmaxf(tmax, __shfl_xor(tmax, 8, 64));
            float mn = fmaxf(mreg[r], tmax);
            corr[r] = __expf(mreg[r] - mn);
            mreg[r] = mn;
            float psum = 0.f;
#pragma unroll
            for (int nf = 0; nf < 4; ++nf) {
                float p = __expf(sc[nf][r] - mn);
                sc[nf][r] = p;
                psum += p;
            }
            psum += __shfl_xor(psum, 1, 64);
            psum += __shfl_xor(psum, 2, 64);
            psum += __shfl_xor(psum, 4, 64);
            psum += __shfl_xor(psum, 8, 64);
            lreg[r] = lreg[r] * corr[r] + psum;
        }
#pragma unroll
        for (int fb = 0; fb < 8; ++fb)
#pragma unroll
            for (int r = 0; r < 4; ++r) oacc[fb][r] *= corr[r];

#pragma unroll
        for (int nf = 0; nf < 4; ++nf)
#pragma unroll
            for (int r = 0; r < 4; ++r)
                Ps[wid][(lhi * 4 + r) * 72 + nf * 16 + l16] = f2bf(sc[nf][r]);

        bf16x8 pa[2];
#pragma unroll
        for (int k2 = 0; k2 < 2; ++k2)
            pa[k2] = *(const bf16x8*)(&Ps[wid][l16 * 72 + k2 * 32 + lhi * 8]);

#pragma unroll
        for (int fb = 0; fb < 8; ++fb) {
            int vrow = fb * 16 + l16;
#pragma unroll
            for (int k2 = 0; k2 < 2; ++k2) {
                bf16x8 vf = *(const bf16x8*)(Vs + vrow * 64 + (((k2 * 4 + lhi) ^ (vrow & 7))) * 8);
                oacc[fb] = __builtin_amdgcn_mfma_f32_16x16x32_bf16(pa[k2], vf, oacc[fb], 0, 0, 0);
            }
        }
    }

    float linv[4];
#pragma unroll
    for (int r = 0; r < 4; ++r) linv[r] = 1.f / lreg[r];
#pragma unroll
    for (int fb = 0; fb < 8; ++fb) {
#pragma unroll
        for (int r = 0; r < 4; ++r) {
            int row = qt * 64 + wid * 16 + lhi * 4 + r;
            o[(size_t)row * D + h * HD + fb * 16 + l16] = oacc[fb][r] * linv[r];
        }
    }
}

// ---------------------------------------------------------------- MoE gate + expert lists
__global__ void gate_kernel(const float* __restrict__ x, const float* __restrict__ gw,
                            float* __restrict__ wbuf, int* __restrict__ cnt, int* __restrict__ elist)
{
    int t = blockIdx.x;
    int g = threadIdx.x >> 4, j = threadIdx.x & 15;
    const float* xr = x + (size_t)t * D;
    const float* gr = gw + (size_t)g * D;
    float p = 0.f;
    for (int m = 0; m < D / 16; ++m) p += xr[j + 16 * m] * gr[j + 16 * m];
    for (int off = 8; off; off >>= 1) p += __shfl_down(p, off, 64);
    __shared__ float lg[NE];
    if (j == 0) lg[g] = p;
    __syncthreads();
    if (threadIdx.x == 0) {
        float l0 = -1e30f; int i0 = 0;
        for (int e = 0; e < NE; ++e) if (lg[e] > l0) { l0 = lg[e]; i0 = e; }
        float l1 = -1e30f; int i1 = 0;
        for (int e = 0; e < NE; ++e) if (e != i0 && lg[e] > l1) { l1 = lg[e]; i1 = e; }
        float rr = expf(l1 - l0);
        wbuf[t * 2 + 0] = 1.f / (1.f + rr);
        wbuf[t * 2 + 1] = rr / (1.f + rr);
        int s0 = atomicAdd(&cnt[i0], 1); elist[i0 * S + s0] = t * 2;
        int s1 = atomicAdd(&cnt[i1], 1); elist[i1 * S + s1] = t * 2 + 1;
    }
}

// ---------------------------------------------------------------- launch
extern "C" void kernel_launch(void* const* d_in, const int* in_sizes, int n_in,
                              void* d_out, int out_size, void* d_ws, size_t ws_size,
                              hipStream_t stream)
{
    const float* hidden = (const float*)d_in[0];
    const float* ln1 = (const float*)d_in[1];
    const float* ln2 = (const float*)d_in[2];
    const float* qn  = (const float*)d_in[3];
    const float* kn  = (const float*)d_in[4];
    const float* Wq  = (const float*)d_in[5];
    const float* Wk  = (const float*)d_in[6];
    const float* Wv  = (const float*)d_in[7];
    const float* Wo  = (const float*)d_in[8];
    const float* gw  = (const float*)d_in[9];
    const float* Wg  = (const float*)d_in[10];
    const float* Wu  = (const float*)d_in[11];
    const float* Wd  = (const float*)d_in[12];
    const int*   pos = (const int*)d_in[13];

    float* ws    = (float*)d_ws;
    float* h1    = ws;                    // 2M floats; overlays qbh/kbh/vbt bf16
    float* qkvb  = h1 + 2097152;          // S*3072 = 3.15M floats
    float* attn  = qkvb + 3145728;        // 2M; overlays abuf bf16
    float* hattn = attn + 2097152;        // 2M
    float* h2    = hattn + 2097152;       // 2M
    float* h2bf  = h2 + 2097152;          // 1M floats as bf16 (S*D ushort)
    float* wbuf  = h2bf + 1048576;        // 2048
    int*   cnt   = (int*)(wbuf + 2048);   // 16
    int*   elist = cnt + 16;              // 16*1024

    unsigned short* qbh = (unsigned short*)h1;                 // S*D bf16
    unsigned short* kbh = (unsigned short*)(h1 + 1048576);     // S*512 bf16
    unsigned short* vbt = (unsigned short*)(h1 + 1310720);     // 512*S bf16
    unsigned short* abuf = (unsigned short*)attn;              // 2048*NI bf16
    unsigned short* h2b  = (unsigned short*)h2bf;              // S*D bf16
    float* out   = (float*)d_out;

    hipMemsetAsync(cnt, 0, NE * sizeof(int), stream);

    rmsnorm_kernel<<<S, 256, 0, stream>>>(hidden, ln1, h1, nullptr);
    qkv_gemm_kernel<<<dim3(48, 16), 256, 0, stream>>>(h1, Wq, Wk, Wv, qkvb);
    // h1 dead; bf16 overlays
    qkrope_bf16_kernel<<<dim3(S, NH + NKV), 64, 0, stream>>>(qkvb, qn, kn, pos, qbh, kbh);
    vtrans_kernel<<<dim3(S / 64, HD / 64, NKV), 256, 0, stream>>>(qkvb, vbt);
    flash_attn_mfma_kernel<<<dim3(S / 64, NH), 256, 0, stream>>>(qbh, kbh, vbt, attn);
    // O projection + residual; also writes out (= hattn) for MoE atomic accumulation
    mfma_gemm_kernel<<<dim3(32, 16), 256, 0, stream>>>(attn, D, Wo, D, hattn, D, hidden, out, S, 2048, D);
    rmsnorm_kernel<<<S, 256, 0, stream>>>(hattn, ln2, h2, h2b);
    gate_kernel<<<S, 256, 0, stream>>>(h2, gw, wbuf, cnt, elist);
    // attn buffer dead; abuf overlays
    moe_mlp_kernel<<<dim3(NI / 16, 16, NE), 256, 0, stream>>>(h2b, Wg, Wu, cnt, elist, abuf);
    moe_down_kernel<<<dim3(D / 16, 16, NE), 256, 0, stream>>>(abuf, Wd, cnt, elist, wbuf, out);
}